// Round 3
// baseline (342.803 us; speedup 1.0000x reference)
//
#include <hip/hip_runtime.h>
#include <stdint.h>

// Problem constants
#define B 8
#define N 2048
#define D 16
#define KNN 32
#define DM 256

// ---------------------------------------------------------------------------
// K1a: per-(b,part) partial fp64 sum/sumsq over 256 rows. grid = B*8.
// ---------------------------------------------------------------------------
__global__ __launch_bounds__(256) void knn_stats_part(
    const float* __restrict__ x, double* __restrict__ Sp, double* __restrict__ Qp)
{
    int blk = blockIdx.x;            // b*8 + part
    int b = blk >> 3, part = blk & 7;
    int tid = threadIdx.x;
    int n = part * 256 + tid;

    const float* row = x + ((size_t)b * N + n) * D;
    double ls[D], lq[D];
#pragma unroll
    for (int d = 0; d < D; d += 4) {
        float4 v = *(const float4*)(row + d);
        double x0 = v.x, x1 = v.y, x2 = v.z, x3 = v.w;
        ls[d] = x0;   lq[d] = x0 * x0;
        ls[d+1] = x1; lq[d+1] = x1 * x1;
        ls[d+2] = x2; lq[d+2] = x2 * x2;
        ls[d+3] = x3; lq[d+3] = x3 * x3;
    }
#pragma unroll
    for (int d = 0; d < D; ++d) {
        double s = ls[d], q = lq[d];
#pragma unroll
        for (int st = 32; st >= 1; st >>= 1) {
            s += __shfl_xor(s, st, 64);
            q += __shfl_xor(q, st, 64);
        }
        ls[d] = s; lq[d] = q;
    }
    __shared__ double sred[4][2 * D];
    int wave = tid >> 6, lane = tid & 63;
    if (lane == 0) {
#pragma unroll
        for (int d = 0; d < D; ++d) {
            sred[wave][d]     = ls[d];
            sred[wave][D + d] = lq[d];
        }
    }
    __syncthreads();
    if (tid < D) {
        int d = tid;
        Sp[blk * D + d] = sred[0][d] + sred[1][d] + sred[2][d] + sred[3][d];
        Qp[blk * D + d] = sred[0][D+d] + sred[1][D+d] + sred[2][D+d] + sred[3][D+d];
    }
}

// ---------------------------------------------------------------------------
// K1b: finalize mean/scale per (b, channel).  1 block x 256 (128 used).
// ---------------------------------------------------------------------------
__global__ __launch_bounds__(256) void knn_stats_final(
    const double* __restrict__ Sp, const double* __restrict__ Qp,
    const float* __restrict__ features,
    float* __restrict__ mean_out, float* __restrict__ scale_out)
{
    int tid = threadIdx.x;
    if (tid >= B * D) return;
    int b = tid >> 4, d = tid & 15;
    double S = 0.0, Q = 0.0;
#pragma unroll
    for (int p = 0; p < 8; ++p) {
        S += Sp[(b * 8 + p) * D + d];
        Q += Qp[(b * 8 + p) * D + d];
    }
    double mean = S / (double)N;
    double var  = (Q - S * S / (double)N) / (double)(N - 1);
    if (var < 0.0) var = 0.0;
    float stdv = (float)sqrt(var);
    float scl  = 1.0f / (stdv + 1e-5f);
    float scl0 = 1.0f / (0.0f + 1e-5f);
    bool mask = features[b * D + d] > 0.1f;
    mean_out [b * 32 + d]      = mask ? 0.0f : (float)mean;
    scale_out[b * 32 + d]      = mask ? scl0 : scl;
    mean_out [b * 32 + 16 + d] = mask ? (float)mean : 0.0f;
    scale_out[b * 32 + 16 + d] = mask ? scl : scl0;
}

// ---------------------------------------------------------------------------
// K2: per-point raw masked x_crd row, sq = sum(x_crd^2), normalized channel
// sums Tc/Tf.  16384 threads.  (arithmetic identical to round 1/2)
// ---------------------------------------------------------------------------
__global__ __launch_bounds__(256) void knn_prep(
    const float* __restrict__ x, const float* __restrict__ features,
    const float* __restrict__ mean_, const float* __restrict__ scale_,
    float* __restrict__ xcrd, float* __restrict__ sq,
    float* __restrict__ Tc, float* __restrict__ Tf)
{
    int t = blockIdx.x * 256 + threadIdx.x;
    int b = t >> 11;
    float tc = 0.f, tf = 0.f, s = 0.f;
    float row[D];
#pragma unroll
    for (int d = 0; d < D; ++d) {
        float xv = x[(size_t)t * D + d];
        bool mask = features[b * D + d] > 0.1f;
        float xc = mask ? 0.f : xv;
        float xf = mask ? xv : 0.f;
        row[d] = xc;
        s += xc * xc;                            // sequential, mirrors ref sq
        float vc = (xc - mean_[b * 32 + d])      * scale_[b * 32 + d];
        vc = fminf(10.f, fmaxf(-10.f, vc));
        float vf = (xf - mean_[b * 32 + 16 + d]) * scale_[b * 32 + 16 + d];
        vf = fminf(10.f, fmaxf(-10.f, vf));
        tc += vc; tf += vf;
    }
#pragma unroll
    for (int d = 0; d < D; d += 4)
        *(float4*)(xcrd + (size_t)t * D + d) =
            make_float4(row[d], row[d+1], row[d+2], row[d+3]);
    sq[t] = s; Tc[t] = tc; Tf[t] = tf;
}

// ---------------------------------------------------------------------------
// K3: transpose W (DM,K)->(K,DM); bias const; pe_loss scalar.  1 block x 256.
// ---------------------------------------------------------------------------
__global__ __launch_bounds__(256) void knn_wprep(
    const float* __restrict__ Wc, const float* __restrict__ Wf,
    const float* __restrict__ pec, const float* __restrict__ pef,
    float* __restrict__ WcT, float* __restrict__ WfT,
    float* __restrict__ cbias, float* __restrict__ pe_loss_out)
{
    int dm = threadIdx.x;
    float cb = 0.f, al = 0.f;
#pragma unroll
    for (int p = 0; p < D; ++p)
        cb += pec[p * DM + dm] + pef[p * DM + dm];
#pragma unroll
    for (int p = 0; p < D; ++p)
        al += fabsf(pec[p * DM + dm]) + fabsf(pef[p * DM + dm]);
    cbias[dm] = cb;
#pragma unroll
    for (int k = 0; k < KNN; ++k) {
        WcT[k * DM + dm] = Wc[dm * KNN + k];
        WfT[k * DM + dm] = Wf[dm * KNN + k];
    }
    __shared__ float red[256];
    red[dm] = al; __syncthreads();
    for (int st = 128; st > 0; st >>= 1) {
        if (dm < st) red[dm] += red[dm + st];
        __syncthreads();
    }
    if (dm == 0) pe_loss_out[0] = red[0];
}

// ---------------------------------------------------------------------------
// K4: one wave per query (4 waves/block, no LDS, no cross-wave interaction).
//  1) fill: 32 keys/lane, key = (dist_bits<<11)|m  (jax tie semantics;
//     distance arithmetic byte-identical to round 1/2).
//  2) per-lane bitonic sort (ascending), static register indices.
//  3) 6 xor-butterfly rounds: C[i] = min(my[i], partner[31-i]) is the exact
//     min-32 of the union (lower half of bitonic merge); re-sort the bitonic
//     result with a 5-stage bitonic merge. min32 over sorted lists is
//     associative+commutative, so the butterfly converges: EVERY lane ends
//     with the identical globally-sorted top-32 in registers.
//  4) matvec: static loop over k, broadcast Tc/Tf loads, no shuffles.
// ---------------------------------------------------------------------------
__global__ __launch_bounds__(256, 4) void knn_main(
    const float* __restrict__ xcrd, const float* __restrict__ sq,
    const float* __restrict__ Tc, const float* __restrict__ Tf,
    const float* __restrict__ WcT, const float* __restrict__ WfT,
    const float* __restrict__ cbias, float* __restrict__ out)
{
    const int lane = threadIdx.x & 63;
    const int qid  = blockIdx.x * 4 + (threadIdx.x >> 6);   // 0..16383
    const int b = qid >> 11;
    const int n = qid & 2047;

    const float* xb  = xcrd + (size_t)b * N * D;
    const float* sqb = sq + b * N;

    // query row
    float qx[D];
#pragma unroll
    for (int d = 0; d < D; d += 4) {
        float4 v = *(const float4*)(xb + (size_t)n * D + d);
        qx[d] = v.x; qx[d+1] = v.y; qx[d+2] = v.z; qx[d+3] = v.w;
    }
    const float sqn = sqb[n];

    // fill 32 candidate keys per lane (m = j*64 + lane)
    unsigned long long key[KNN];
#pragma unroll
    for (int j = 0; j < KNN; ++j) {
        int m = j * 64 + lane;
        const float* xm = xb + (size_t)m * D;
        float mr[D];
#pragma unroll
        for (int d = 0; d < D; d += 4) {
            float4 v = *(const float4*)(xm + d);
            mr[d] = v.x; mr[d+1] = v.y; mr[d+2] = v.z; mr[d+3] = v.w;
        }
        float dot = 0.f;
#pragma unroll
        for (int d = 0; d < D; ++d) dot += qx[d] * mr[d];  // sequential: self-dist == 0
        float d2 = sqn + sqb[m] - 2.0f * dot;
        float dist = sqrtf(fmaxf(d2, 0.f));
        key[j] = ((unsigned long long)__float_as_uint(dist) << 11) | (unsigned)m;
    }

    // in-register bitonic sort, ascending (static indices only)
#pragma unroll
    for (int kk = 2; kk <= KNN; kk <<= 1) {
#pragma unroll
        for (int jj = kk >> 1; jj > 0; jj >>= 1) {
#pragma unroll
            for (int i = 0; i < KNN; ++i) {
                int l = i ^ jj;
                if (l > i) {
                    bool asc = ((i & kk) == 0);
                    unsigned long long a = key[i], c = key[l];
                    bool sw = asc ? (a > c) : (a < c);
                    key[i] = sw ? c : a;
                    key[l] = sw ? a : c;
                }
            }
        }
    }

    // 6 butterfly rounds; round body kept as a rolled loop (code size).
#pragma unroll 1
    for (int s = 1; s <= 32; s <<= 1) {
        // pairwise exchange: C[i] = min(my[i], partner[31-i]); slots {i,31-i}
        // are disjoint per iteration, shuffles read pre-update values.
#pragma unroll
        for (int i = 0; i < KNN / 2; ++i) {
            int r = KNN - 1 - i;
            unsigned long long o_i = __shfl_xor(key[r], s, 64); // partner[31-i]
            unsigned long long o_r = __shfl_xor(key[i], s, 64); // partner[31-r]
            key[i] = (o_i < key[i]) ? o_i : key[i];
            key[r] = (o_r < key[r]) ? o_r : key[r];
        }
        // re-sort bitonic sequence ascending: 5-stage bitonic merge
#pragma unroll
        for (int jj = 16; jj >= 1; jj >>= 1) {
#pragma unroll
            for (int i = 0; i < KNN; ++i) {
                if ((i & jj) == 0) {
                    int l = i + jj;
                    unsigned long long a = key[i], c = key[l];
                    bool sw = (c < a);
                    key[i] = sw ? c : a;
                    key[l] = sw ? a : c;
                }
            }
        }
    }

    // matvec: all lanes hold identical sorted top-32
    float acc[4] = {0.f, 0.f, 0.f, 0.f};
    const float* Tcb = Tc + b * N;
    const float* Tfb = Tf + b * N;
    const float Tcn = Tcb[n], Tfn = Tfb[n];

#pragma unroll
    for (int k = 0; k < KNN; ++k) {
        int wm = (int)(key[k] & 2047u);
        float ak = Tcb[wm] - Tcn;
        float bk = Tfb[wm] - Tfn;
        const float* wc = WcT + k * DM + lane;
        const float* wf = WfT + k * DM + lane;
#pragma unroll
        for (int q = 0; q < 4; ++q)
            acc[q] += wc[q * 64] * ak + wf[q * 64] * bk;
    }

    size_t obase = (size_t)qid * DM + lane;
#pragma unroll
    for (int q = 0; q < 4; ++q)
        out[obase + q * 64] = acc[q] + cbias[lane + q * 64];
}

// ---------------------------------------------------------------------------
extern "C" void kernel_launch(void* const* d_in, const int* in_sizes, int n_in,
                              void* d_out, int out_size, void* d_ws, size_t ws_size,
                              hipStream_t stream)
{
    const float* x        = (const float*)d_in[0];   // (B,N,D)
    const float* features = (const float*)d_in[1];   // (B,D)
    const float* W_crd    = (const float*)d_in[2];   // (DM,K)
    const float* W_ftr    = (const float*)d_in[3];   // (DM,K)
    const float* pe_crd   = (const float*)d_in[4];   // (1,1,D,DM)
    const float* pe_ftr   = (const float*)d_in[5];   // (1,1,D,DM)
    // d_in[6] = k (constant 32), ignored

    float* out = (float*)d_out;                      // B*N*DM floats + 1 (pe_loss)

    // workspace layout: doubles first (8-byte alignment)
    double* Sp = (double*)d_ws;                      // B*8*16
    double* Qp = Sp + B * 8 * D;                     // B*8*16
    float* xcrd  = (float*)(Qp + B * 8 * D);         // 262144
    float* sqv   = xcrd + (size_t)B * N * D;         // 16384
    float* Tc    = sqv  + B * N;                     // 16384
    float* Tf    = Tc   + B * N;                     // 16384
    float* mean_ = Tf   + B * N;                     // 256
    float* scale = mean_ + B * 32;                   // 256
    float* cbias = scale + B * 32;                   // 256
    float* WcT   = cbias + DM;                       // 8192
    float* WfT   = WcT + KNN * DM;                   // 8192

    knn_stats_part <<<B * 8, 256, 0, stream>>>(x, Sp, Qp);
    knn_stats_final<<<1, 256, 0, stream>>>(Sp, Qp, features, mean_, scale);
    knn_prep <<<B * N / 256, 256, 0, stream>>>(x, features, mean_, scale,
                                               xcrd, sqv, Tc, Tf);
    knn_wprep<<<1, 256, 0, stream>>>(W_crd, W_ftr, pe_crd, pe_ftr,
                                     WcT, WfT, cbias, out + (size_t)out_size - 1);
    knn_main <<<B * N / 4, 256, 0, stream>>>(xcrd, sqv, Tc, Tf,
                                             WcT, WfT, cbias, out);
}

// Round 4
// 324.418 us; speedup vs baseline: 1.0567x; 1.0567x over previous
//
#include <hip/hip_runtime.h>
#include <stdint.h>

// Problem constants
#define B 8
#define N 2048
#define D 16
#define KNN 32
#define DM 256

// ---------------------------------------------------------------------------
// K1: blocks 0..63: per-(b,part) partial fp64 sum/sumsq over 256 rows.
//     block 64:     W transpose + pe bias/loss (independent inputs).
// ---------------------------------------------------------------------------
__global__ __launch_bounds__(256) void knn_pre(
    const float* __restrict__ x,
    const float* __restrict__ Wc, const float* __restrict__ Wf,
    const float* __restrict__ pec, const float* __restrict__ pef,
    double* __restrict__ Sp, double* __restrict__ Qp,
    float* __restrict__ WcT, float* __restrict__ WfT,
    float* __restrict__ cbias, float* __restrict__ pe_loss_out)
{
    if (blockIdx.x == 64) {
        // ---- wprep body ----
        int dm = threadIdx.x;
        float cb = 0.f, al = 0.f;
#pragma unroll
        for (int p = 0; p < D; ++p)
            cb += pec[p * DM + dm] + pef[p * DM + dm];
#pragma unroll
        for (int p = 0; p < D; ++p)
            al += fabsf(pec[p * DM + dm]) + fabsf(pef[p * DM + dm]);
        cbias[dm] = cb;
#pragma unroll
        for (int k = 0; k < KNN; ++k) {
            WcT[k * DM + dm] = Wc[dm * KNN + k];
            WfT[k * DM + dm] = Wf[dm * KNN + k];
        }
        __shared__ float red[256];
        red[dm] = al; __syncthreads();
        for (int st = 128; st > 0; st >>= 1) {
            if (dm < st) red[dm] += red[dm + st];
            __syncthreads();
        }
        if (dm == 0) pe_loss_out[0] = red[0];
        return;
    }

    // ---- stats partial body ----
    int blk = blockIdx.x;            // b*8 + part
    int b = blk >> 3, part = blk & 7;
    int tid = threadIdx.x;
    int n = part * 256 + tid;

    const float* row = x + ((size_t)b * N + n) * D;
    double ls[D], lq[D];
#pragma unroll
    for (int d = 0; d < D; d += 4) {
        float4 v = *(const float4*)(row + d);
        double x0 = v.x, x1 = v.y, x2 = v.z, x3 = v.w;
        ls[d] = x0;   lq[d] = x0 * x0;
        ls[d+1] = x1; lq[d+1] = x1 * x1;
        ls[d+2] = x2; lq[d+2] = x2 * x2;
        ls[d+3] = x3; lq[d+3] = x3 * x3;
    }
#pragma unroll
    for (int d = 0; d < D; ++d) {
        double s = ls[d], q = lq[d];
#pragma unroll
        for (int st = 32; st >= 1; st >>= 1) {
            s += __shfl_xor(s, st, 64);
            q += __shfl_xor(q, st, 64);
        }
        ls[d] = s; lq[d] = q;
    }
    __shared__ double sred[4][2 * D];
    int wave = tid >> 6, lane = tid & 63;
    if (lane == 0) {
#pragma unroll
        for (int d = 0; d < D; ++d) {
            sred[wave][d]     = ls[d];
            sred[wave][D + d] = lq[d];
        }
    }
    __syncthreads();
    if (tid < D) {
        int d = tid;
        Sp[blk * D + d] = sred[0][d] + sred[1][d] + sred[2][d] + sred[3][d];
        Qp[blk * D + d] = sred[0][D+d] + sred[1][D+d] + sred[2][D+d] + sred[3][D+d];
    }
}

// ---------------------------------------------------------------------------
// K2: fused finalize+prep. Each block (256 rows, all one batch) recomputes
// the tiny fp64 finalize into LDS, then per-point: masked x_crd row, sq,
// normalized channel sums Tc/Tf.  Arithmetic identical to rounds 1-3.
// ---------------------------------------------------------------------------
__global__ __launch_bounds__(256) void knn_prep(
    const float* __restrict__ x, const float* __restrict__ features,
    const double* __restrict__ Sp, const double* __restrict__ Qp,
    float* __restrict__ xcrd, float* __restrict__ sq,
    float* __restrict__ Tc, float* __restrict__ Tf)
{
    int t = blockIdx.x * 256 + threadIdx.x;      // (b,n) flat
    int b = t >> 11;                             // constant within block

    __shared__ float smean[32], sscale[32];
    if (threadIdx.x < D) {
        int d = threadIdx.x;
        double S = 0.0, Q = 0.0;
#pragma unroll
        for (int p = 0; p < 8; ++p) {
            S += Sp[(b * 8 + p) * D + d];
            Q += Qp[(b * 8 + p) * D + d];
        }
        double mean = S / (double)N;
        double var  = (Q - S * S / (double)N) / (double)(N - 1);
        if (var < 0.0) var = 0.0;
        float stdv = (float)sqrt(var);
        float scl  = 1.0f / (stdv + 1e-5f);
        float scl0 = 1.0f / (0.0f + 1e-5f);
        bool mask = features[b * D + d] > 0.1f;
        smean [d]      = mask ? 0.0f : (float)mean;
        sscale[d]      = mask ? scl0 : scl;
        smean [16 + d] = mask ? (float)mean : 0.0f;
        sscale[16 + d] = mask ? scl : scl0;
    }
    __syncthreads();

    float tc = 0.f, tf = 0.f, s = 0.f;
    float row[D];
#pragma unroll
    for (int d = 0; d < D; ++d) {
        float xv = x[(size_t)t * D + d];
        bool mask = features[b * D + d] > 0.1f;
        float xc = mask ? 0.f : xv;
        float xf = mask ? xv : 0.f;
        row[d] = xc;
        s += xc * xc;                            // sequential, mirrors ref sq
        float vc = (xc - smean[d])      * sscale[d];
        vc = fminf(10.f, fmaxf(-10.f, vc));
        float vf = (xf - smean[16 + d]) * sscale[16 + d];
        vf = fminf(10.f, fmaxf(-10.f, vf));
        tc += vc; tf += vf;
    }
#pragma unroll
    for (int d = 0; d < D; d += 4)
        *(float4*)(xcrd + (size_t)t * D + d) =
            make_float4(row[d], row[d+1], row[d+2], row[d+3]);
    sq[t] = s; Tc[t] = tc; Tf[t] = tf;
}

// ---------------------------------------------------------------------------
// K4: one wave per query (4 waves/block, no LDS, no cross-wave interaction).
//  1) fill: 32 keys/lane, key = (dist_bits<<11)|m  (jax tie semantics;
//     distance arithmetic byte-identical to rounds 1-3).
//  2) per-lane bitonic sort (ascending), static register indices.
//  3) 6 xor-butterfly rounds: C[i] = min(my[i], partner[31-i]) = exact
//     min-32 of the union (lower half of bitonic merge); re-sort with a
//     5-stage bitonic merge. Every lane converges to the identical
//     globally-sorted top-32 in registers.
//  4) matvec: static loop over k, no shuffles.
// __launch_bounds__(256,2): VGPR budget 256 — round 3's (256,4) made the
// allocator spill the 64-VGPR key array to scratch (WRITE_SIZE 16->41 MB).
// ---------------------------------------------------------------------------
__global__ __launch_bounds__(256, 2) void knn_main(
    const float* __restrict__ xcrd, const float* __restrict__ sq,
    const float* __restrict__ Tc, const float* __restrict__ Tf,
    const float* __restrict__ WcT, const float* __restrict__ WfT,
    const float* __restrict__ cbias, float* __restrict__ out)
{
    const int lane = threadIdx.x & 63;
    const int qid  = blockIdx.x * 4 + (threadIdx.x >> 6);   // 0..16383
    const int b = qid >> 11;
    const int n = qid & 2047;

    const float* xb  = xcrd + (size_t)b * N * D;
    const float* sqb = sq + b * N;

    // query row
    float qx[D];
#pragma unroll
    for (int d = 0; d < D; d += 4) {
        float4 v = *(const float4*)(xb + (size_t)n * D + d);
        qx[d] = v.x; qx[d+1] = v.y; qx[d+2] = v.z; qx[d+3] = v.w;
    }
    const float sqn = sqb[n];

    // fill 32 candidate keys per lane (m = j*64 + lane)
    unsigned long long key[KNN];
#pragma unroll
    for (int j = 0; j < KNN; ++j) {
        int m = j * 64 + lane;
        const float* xm = xb + (size_t)m * D;
        float4 v0 = *(const float4*)(xm);
        float4 v1 = *(const float4*)(xm + 4);
        float4 v2 = *(const float4*)(xm + 8);
        float4 v3 = *(const float4*)(xm + 12);
        float dot = 0.f;
        dot += qx[0]  * v0.x; dot += qx[1]  * v0.y;
        dot += qx[2]  * v0.z; dot += qx[3]  * v0.w;
        dot += qx[4]  * v1.x; dot += qx[5]  * v1.y;
        dot += qx[6]  * v1.z; dot += qx[7]  * v1.w;
        dot += qx[8]  * v2.x; dot += qx[9]  * v2.y;
        dot += qx[10] * v2.z; dot += qx[11] * v2.w;
        dot += qx[12] * v3.x; dot += qx[13] * v3.y;
        dot += qx[14] * v3.z; dot += qx[15] * v3.w;
        float d2 = sqn + sqb[m] - 2.0f * dot;
        float dist = sqrtf(fmaxf(d2, 0.f));
        key[j] = ((unsigned long long)__float_as_uint(dist) << 11) | (unsigned)m;
    }

    // in-register bitonic sort, ascending (static indices only)
#pragma unroll
    for (int kk = 2; kk <= KNN; kk <<= 1) {
#pragma unroll
        for (int jj = kk >> 1; jj > 0; jj >>= 1) {
#pragma unroll
            for (int i = 0; i < KNN; ++i) {
                int l = i ^ jj;
                if (l > i) {
                    bool asc = ((i & kk) == 0);
                    unsigned long long a = key[i], c = key[l];
                    bool sw = asc ? (a > c) : (a < c);
                    key[i] = sw ? c : a;
                    key[l] = sw ? a : c;
                }
            }
        }
    }

    // 6 butterfly rounds; round body kept as a rolled loop (code size).
#pragma unroll 1
    for (int s = 1; s <= 32; s <<= 1) {
        // pairwise exchange: C[i] = min(my[i], partner[31-i]); slots {i,31-i}
        // are disjoint per iteration, shuffles read pre-update values.
#pragma unroll
        for (int i = 0; i < KNN / 2; ++i) {
            int r = KNN - 1 - i;
            unsigned long long o_i = __shfl_xor(key[r], s, 64); // partner[31-i]
            unsigned long long o_r = __shfl_xor(key[i], s, 64); // partner[31-r]
            key[i] = (o_i < key[i]) ? o_i : key[i];
            key[r] = (o_r < key[r]) ? o_r : key[r];
        }
        // re-sort bitonic sequence ascending: 5-stage bitonic merge
#pragma unroll
        for (int jj = 16; jj >= 1; jj >>= 1) {
#pragma unroll
            for (int i = 0; i < KNN; ++i) {
                if ((i & jj) == 0) {
                    int l = i + jj;
                    unsigned long long a = key[i], c = key[l];
                    bool sw = (c < a);
                    key[i] = sw ? c : a;
                    key[l] = sw ? a : c;
                }
            }
        }
    }

    // matvec: all lanes hold identical sorted top-32
    float acc[4] = {0.f, 0.f, 0.f, 0.f};
    const float* Tcb = Tc + b * N;
    const float* Tfb = Tf + b * N;
    const float Tcn = Tcb[n], Tfn = Tfb[n];

#pragma unroll
    for (int k = 0; k < KNN; ++k) {
        int wm = (int)(key[k] & 2047u);
        float ak = Tcb[wm] - Tcn;
        float bk = Tfb[wm] - Tfn;
        const float* wc = WcT + k * DM + lane;
        const float* wf = WfT + k * DM + lane;
#pragma unroll
        for (int q = 0; q < 4; ++q)
            acc[q] += wc[q * 64] * ak + wf[q * 64] * bk;
    }

    size_t obase = (size_t)qid * DM + lane;
#pragma unroll
    for (int q = 0; q < 4; ++q)
        out[obase + q * 64] = acc[q] + cbias[lane + q * 64];
}

// ---------------------------------------------------------------------------
extern "C" void kernel_launch(void* const* d_in, const int* in_sizes, int n_in,
                              void* d_out, int out_size, void* d_ws, size_t ws_size,
                              hipStream_t stream)
{
    const float* x        = (const float*)d_in[0];   // (B,N,D)
    const float* features = (const float*)d_in[1];   // (B,D)
    const float* W_crd    = (const float*)d_in[2];   // (DM,K)
    const float* W_ftr    = (const float*)d_in[3];   // (DM,K)
    const float* pe_crd   = (const float*)d_in[4];   // (1,1,D,DM)
    const float* pe_ftr   = (const float*)d_in[5];   // (1,1,D,DM)
    // d_in[6] = k (constant 32), ignored

    float* out = (float*)d_out;                      // B*N*DM floats + 1 (pe_loss)

    // workspace layout: doubles first (8-byte alignment)
    double* Sp = (double*)d_ws;                      // B*8*16
    double* Qp = Sp + B * 8 * D;                     // B*8*16
    float* xcrd  = (float*)(Qp + B * 8 * D);         // 262144
    float* sqv   = xcrd + (size_t)B * N * D;         // 16384
    float* Tc    = sqv  + B * N;                     // 16384
    float* Tf    = Tc   + B * N;                     // 16384
    float* cbias = Tf   + B * N;                     // 256
    float* WcT   = cbias + DM;                       // 8192
    float* WfT   = WcT + KNN * DM;                   // 8192

    knn_pre <<<B * 8 + 1, 256, 0, stream>>>(x, W_crd, W_ftr, pe_crd, pe_ftr,
                                            Sp, Qp, WcT, WfT, cbias,
                                            out + (size_t)out_size - 1);
    knn_prep<<<B * N / 256, 256, 0, stream>>>(x, features, Sp, Qp,
                                              xcrd, sqv, Tc, Tf);
    knn_main<<<B * N / 4, 256, 0, stream>>>(xcrd, sqv, Tc, Tf,
                                            WcT, WfT, cbias, out);
}

// Round 5
// 295.263 us; speedup vs baseline: 1.1610x; 1.0987x over previous
//
#include <hip/hip_runtime.h>
#include <stdint.h>

// Problem constants
#define B 8
#define N 2048
#define D 16
#define KNN 32
#define DM 256

// ---------------------------------------------------------------------------
// K1: fused prep. Blocks 0..63: recompute own-batch fp64 stats (mean/scale)
// then per-point masked x_crd row, sq, normalized channel sums Tc/Tf.
// Block 64: W transpose + pe bias/loss.  Arithmetic identical to rounds 1-4.
// ---------------------------------------------------------------------------
__global__ __launch_bounds__(256) void knn_prep(
    const float* __restrict__ x, const float* __restrict__ features,
    const float* __restrict__ Wc, const float* __restrict__ Wf,
    const float* __restrict__ pec, const float* __restrict__ pef,
    float* __restrict__ xcrd, float* __restrict__ sq,
    float* __restrict__ Tc, float* __restrict__ Tf,
    float* __restrict__ WcT, float* __restrict__ WfT,
    float* __restrict__ cbias, float* __restrict__ pe_loss_out)
{
    if (blockIdx.x == 64) {
        // ---- wprep body ----
        int dm = threadIdx.x;
        float cb = 0.f, al = 0.f;
#pragma unroll
        for (int p = 0; p < D; ++p)
            cb += pec[p * DM + dm] + pef[p * DM + dm];
#pragma unroll
        for (int p = 0; p < D; ++p)
            al += fabsf(pec[p * DM + dm]) + fabsf(pef[p * DM + dm]);
        cbias[dm] = cb;
#pragma unroll
        for (int k = 0; k < KNN; ++k) {
            WcT[k * DM + dm] = Wc[dm * KNN + k];
            WfT[k * DM + dm] = Wf[dm * KNN + k];
        }
        __shared__ float redf[256];
        redf[dm] = al; __syncthreads();
        for (int st = 128; st > 0; st >>= 1) {
            if (dm < st) redf[dm] += redf[dm + st];
            __syncthreads();
        }
        if (dm == 0) pe_loss_out[0] = redf[0];
        return;
    }

    int tid = threadIdx.x;
    int b = blockIdx.x >> 3;

    // ---- own-batch stats: 8 rows per thread, fp64 accumulate ----
    double ls[D], lq[D];
#pragma unroll
    for (int d = 0; d < D; ++d) { ls[d] = 0.0; lq[d] = 0.0; }
    for (int r = 0; r < 8; ++r) {
        const float* row = x + ((size_t)b * N + r * 256 + tid) * D;
#pragma unroll
        for (int d = 0; d < D; d += 4) {
            float4 v = *(const float4*)(row + d);
            double x0 = v.x, x1 = v.y, x2 = v.z, x3 = v.w;
            ls[d]   += x0; lq[d]   += x0 * x0;
            ls[d+1] += x1; lq[d+1] += x1 * x1;
            ls[d+2] += x2; lq[d+2] += x2 * x2;
            ls[d+3] += x3; lq[d+3] += x3 * x3;
        }
    }
#pragma unroll
    for (int d = 0; d < D; ++d) {
        double s = ls[d], q = lq[d];
#pragma unroll
        for (int st = 32; st >= 1; st >>= 1) {
            s += __shfl_xor(s, st, 64);
            q += __shfl_xor(q, st, 64);
        }
        ls[d] = s; lq[d] = q;
    }
    __shared__ double sred[4][2 * D];
    __shared__ float smean[32], sscale[32];
    int wave = tid >> 6, lane = tid & 63;
    if (lane == 0) {
#pragma unroll
        for (int d = 0; d < D; ++d) {
            sred[wave][d]     = ls[d];
            sred[wave][D + d] = lq[d];
        }
    }
    __syncthreads();
    if (tid < D) {
        int d = tid;
        double S = sred[0][d] + sred[1][d] + sred[2][d] + sred[3][d];
        double Q = sred[0][D+d] + sred[1][D+d] + sred[2][D+d] + sred[3][D+d];
        double mean = S / (double)N;
        double var  = (Q - S * S / (double)N) / (double)(N - 1);
        if (var < 0.0) var = 0.0;
        float stdv = (float)sqrt(var);
        float scl  = 1.0f / (stdv + 1e-5f);
        float scl0 = 1.0f / (0.0f + 1e-5f);
        bool mask = features[b * D + d] > 0.1f;
        smean [d]      = mask ? 0.0f : (float)mean;
        sscale[d]      = mask ? scl0 : scl;
        smean [16 + d] = mask ? (float)mean : 0.0f;
        sscale[16 + d] = mask ? scl : scl0;
    }
    __syncthreads();

    // ---- per-point processing (row t, same mapping as rounds 1-4) ----
    int t = blockIdx.x * 256 + tid;
    float tc = 0.f, tf = 0.f, s = 0.f;
    float row[D];
#pragma unroll
    for (int d = 0; d < D; ++d) {
        float xv = x[(size_t)t * D + d];
        bool mask = features[b * D + d] > 0.1f;
        float xc = mask ? 0.f : xv;
        float xf = mask ? xv : 0.f;
        row[d] = xc;
        s += xc * xc;                            // sequential, mirrors ref sq
        float vc = (xc - smean[d])      * sscale[d];
        vc = fminf(10.f, fmaxf(-10.f, vc));
        float vf = (xf - smean[16 + d]) * sscale[16 + d];
        vf = fminf(10.f, fmaxf(-10.f, vf));
        tc += vc; tf += vf;
    }
#pragma unroll
    for (int d = 0; d < D; d += 4)
        *(float4*)(xcrd + (size_t)t * D + d) =
            make_float4(row[d], row[d+1], row[d+2], row[d+3]);
    sq[t] = s; Tc[t] = tc; Tf[t] = tf;
}

// ---------------------------------------------------------------------------
// K2: one wave (one 64-thread block) per query, no LDS.
//  Keys are doubles: bits = (1023<<52) | (dist_bits<<11) | m  — a normal
//  positive double in [1,2). Positive-float bit order == numeric order, so
//  compare-exchanges become v_min_f64/v_max_f64 (2 insts vs 5 for u64 CE).
//  Tie semantics (dist asc, index asc) preserved exactly; keys globally
//  unique (distinct m), so fmin/fmax never see equal operands or NaN.
//  1) fill 32 keys/lane (distance arithmetic byte-identical to rounds 1-4)
//  2) per-lane bitonic sort (static register indices)
//  3) 6 xor-butterfly rounds: keep-min-32 exchange + 5-stage bitonic merge;
//     all 64 lanes converge to the identical global sorted top-32
//  4) matvec, coalesced store.
// __launch_bounds__(64,2): 1 wave/block, 256-VGPR budget — avoid the
// 64-arch-VGPR + AGPR-move split seen in rounds 3/4.
// ---------------------------------------------------------------------------
__global__ __launch_bounds__(64, 2) void knn_main(
    const float* __restrict__ xcrd, const float* __restrict__ sq,
    const float* __restrict__ Tc, const float* __restrict__ Tf,
    const float* __restrict__ WcT, const float* __restrict__ WfT,
    const float* __restrict__ cbias, float* __restrict__ out)
{
    const int lane = threadIdx.x;
    const int qid  = blockIdx.x;                 // 0..16383
    const int b = qid >> 11;
    const int n = qid & 2047;

    const float* xb  = xcrd + (size_t)b * N * D;
    const float* sqb = sq + b * N;

    // query row
    float qx[D];
#pragma unroll
    for (int d = 0; d < D; d += 4) {
        float4 v = *(const float4*)(xb + (size_t)n * D + d);
        qx[d] = v.x; qx[d+1] = v.y; qx[d+2] = v.z; qx[d+3] = v.w;
    }
    const float sqn = sqb[n];

    // fill 32 candidate keys per lane (m = j*64 + lane)
    double key[KNN];
#pragma unroll
    for (int j = 0; j < KNN; ++j) {
        int m = j * 64 + lane;
        const float* xm = xb + (size_t)m * D;
        float4 v0 = *(const float4*)(xm);
        float4 v1 = *(const float4*)(xm + 4);
        float4 v2 = *(const float4*)(xm + 8);
        float4 v3 = *(const float4*)(xm + 12);
        float dot = 0.f;
        dot += qx[0]  * v0.x; dot += qx[1]  * v0.y;
        dot += qx[2]  * v0.z; dot += qx[3]  * v0.w;
        dot += qx[4]  * v1.x; dot += qx[5]  * v1.y;
        dot += qx[6]  * v1.z; dot += qx[7]  * v1.w;
        dot += qx[8]  * v2.x; dot += qx[9]  * v2.y;
        dot += qx[10] * v2.z; dot += qx[11] * v2.w;
        dot += qx[12] * v3.x; dot += qx[13] * v3.y;
        dot += qx[14] * v3.z; dot += qx[15] * v3.w;
        float d2 = sqn + sqb[m] - 2.0f * dot;
        float dist = sqrtf(fmaxf(d2, 0.f));
        unsigned long long u = (0x3FFULL << 52)
            | ((unsigned long long)__float_as_uint(dist) << 11)
            | (unsigned)m;
        key[j] = __longlong_as_double(u);
    }

    // in-register bitonic sort, ascending (static indices, min/max CEs)
#pragma unroll
    for (int kk = 2; kk <= KNN; kk <<= 1) {
#pragma unroll
        for (int jj = kk >> 1; jj > 0; jj >>= 1) {
#pragma unroll
            for (int i = 0; i < KNN; ++i) {
                int l = i ^ jj;
                if (l > i) {
                    double a = key[i], c = key[l];
                    if ((i & kk) == 0) { key[i] = fmin(a, c); key[l] = fmax(a, c); }
                    else               { key[i] = fmax(a, c); key[l] = fmin(a, c); }
                }
            }
        }
    }

    // 6 butterfly rounds; round body kept as a rolled loop (code size).
#pragma unroll 1
    for (int s = 1; s <= 32; s <<= 1) {
        // keep-min-32 exchange: C[i] = min(my[i], partner[31-i]); slots
        // {i,31-i} disjoint per iteration, shuffles read pre-update values.
#pragma unroll
        for (int i = 0; i < KNN / 2; ++i) {
            int r = KNN - 1 - i;
            double o_i = __shfl_xor(key[r], s, 64); // partner[31-i]
            double o_r = __shfl_xor(key[i], s, 64); // partner[31-r]
            key[i] = fmin(key[i], o_i);
            key[r] = fmin(key[r], o_r);
        }
        // re-sort bitonic sequence ascending: 5-stage bitonic merge
#pragma unroll
        for (int jj = 16; jj >= 1; jj >>= 1) {
#pragma unroll
            for (int i = 0; i < KNN; ++i) {
                if ((i & jj) == 0) {
                    int l = i + jj;
                    double a = key[i], c = key[l];
                    key[i] = fmin(a, c);
                    key[l] = fmax(a, c);
                }
            }
        }
    }

    // matvec: all lanes hold identical sorted top-32
    float acc[4] = {0.f, 0.f, 0.f, 0.f};
    const float* Tcb = Tc + b * N;
    const float* Tfb = Tf + b * N;
    const float Tcn = Tcb[n], Tfn = Tfb[n];

#pragma unroll
    for (int k = 0; k < KNN; ++k) {
        int wm = (int)(__double_as_longlong(key[k]) & 2047);
        float ak = Tcb[wm] - Tcn;
        float bk = Tfb[wm] - Tfn;
        const float* wc = WcT + k * DM + lane;
        const float* wf = WfT + k * DM + lane;
#pragma unroll
        for (int q = 0; q < 4; ++q)
            acc[q] += wc[q * 64] * ak + wf[q * 64] * bk;
    }

    size_t obase = (size_t)qid * DM + lane;
#pragma unroll
    for (int q = 0; q < 4; ++q)
        out[obase + q * 64] = acc[q] + cbias[lane + q * 64];
}

// ---------------------------------------------------------------------------
extern "C" void kernel_launch(void* const* d_in, const int* in_sizes, int n_in,
                              void* d_out, int out_size, void* d_ws, size_t ws_size,
                              hipStream_t stream)
{
    const float* x        = (const float*)d_in[0];   // (B,N,D)
    const float* features = (const float*)d_in[1];   // (B,D)
    const float* W_crd    = (const float*)d_in[2];   // (DM,K)
    const float* W_ftr    = (const float*)d_in[3];   // (DM,K)
    const float* pe_crd   = (const float*)d_in[4];   // (1,1,D,DM)
    const float* pe_ftr   = (const float*)d_in[5];   // (1,1,D,DM)
    // d_in[6] = k (constant 32), ignored

    float* out = (float*)d_out;                      // B*N*DM floats + 1 (pe_loss)

    float* xcrd  = (float*)d_ws;                     // 262144
    float* sqv   = xcrd + (size_t)B * N * D;         // 16384
    float* Tc    = sqv  + B * N;                     // 16384
    float* Tf    = Tc   + B * N;                     // 16384
    float* cbias = Tf   + B * N;                     // 256
    float* WcT   = cbias + DM;                       // 8192
    float* WfT   = WcT + KNN * DM;                   // 8192

    knn_prep<<<65, 256, 0, stream>>>(x, features, W_crd, W_ftr, pe_crd, pe_ftr,
                                     xcrd, sqv, Tc, Tf, WcT, WfT, cbias,
                                     out + (size_t)out_size - 1);
    knn_main<<<B * N, 64, 0, stream>>>(xcrd, sqv, Tc, Tf,
                                       WcT, WfT, cbias, out);
}

// Round 8
// 247.673 us; speedup vs baseline: 1.3841x; 1.1921x over previous
//
#include <hip/hip_runtime.h>
#include <stdint.h>

// Problem constants
#define B 8
#define N 2048
#define D 16
#define KNN 32
#define DM 256
#define CAP 96   // tie-fixup cap; degenerate all-tie batches still rank correctly

// ---------------------------------------------------------------------------
// K1: fused prep (round-5 PROVEN, verbatim). Blocks 0..63: own-batch fp64
// stats, then per-point masked x_crd row -> xcrd, sq, Tc/Tf.
// Block 64: W transpose + pe bias/loss.
// ---------------------------------------------------------------------------
__global__ __launch_bounds__(256) void knn_prep(
    const float* __restrict__ x, const float* __restrict__ features,
    const float* __restrict__ Wc, const float* __restrict__ Wf,
    const float* __restrict__ pec, const float* __restrict__ pef,
    float* __restrict__ xcrd, float* __restrict__ sq,
    float* __restrict__ Tc, float* __restrict__ Tf,
    float* __restrict__ WcT, float* __restrict__ WfT,
    float* __restrict__ cbias, float* __restrict__ pe_loss_out)
{
    if (blockIdx.x == 64) {
        int dm = threadIdx.x;
        float cb = 0.f, al = 0.f;
#pragma unroll
        for (int p = 0; p < D; ++p)
            cb += pec[p * DM + dm] + pef[p * DM + dm];
#pragma unroll
        for (int p = 0; p < D; ++p)
            al += fabsf(pec[p * DM + dm]) + fabsf(pef[p * DM + dm]);
        cbias[dm] = cb;
#pragma unroll
        for (int k = 0; k < KNN; ++k) {
            WcT[k * DM + dm] = Wc[dm * KNN + k];
            WfT[k * DM + dm] = Wf[dm * KNN + k];
        }
        __shared__ float redf[256];
        redf[dm] = al; __syncthreads();
        for (int st = 128; st > 0; st >>= 1) {
            if (dm < st) redf[dm] += redf[dm + st];
            __syncthreads();
        }
        if (dm == 0) pe_loss_out[0] = redf[0];
        return;
    }

    int tid = threadIdx.x;
    int b = blockIdx.x >> 3;

    // ---- own-batch stats: 8 rows per thread, fp64 accumulate ----
    double ls[D], lq[D];
#pragma unroll
    for (int d = 0; d < D; ++d) { ls[d] = 0.0; lq[d] = 0.0; }
    for (int r = 0; r < 8; ++r) {
        const float* row = x + ((size_t)b * N + r * 256 + tid) * D;
#pragma unroll
        for (int d = 0; d < D; d += 4) {
            float4 v = *(const float4*)(row + d);
            double x0 = v.x, x1 = v.y, x2 = v.z, x3 = v.w;
            ls[d]   += x0; lq[d]   += x0 * x0;
            ls[d+1] += x1; lq[d+1] += x1 * x1;
            ls[d+2] += x2; lq[d+2] += x2 * x2;
            ls[d+3] += x3; lq[d+3] += x3 * x3;
        }
    }
#pragma unroll
    for (int d = 0; d < D; ++d) {
        double s = ls[d], q = lq[d];
#pragma unroll
        for (int st = 32; st >= 1; st >>= 1) {
            s += __shfl_xor(s, st, 64);
            q += __shfl_xor(q, st, 64);
        }
        ls[d] = s; lq[d] = q;
    }
    __shared__ double sred[4][2 * D];
    __shared__ float smean[32], sscale[32];
    int wave = tid >> 6, lane = tid & 63;
    if (lane == 0) {
#pragma unroll
        for (int d = 0; d < D; ++d) {
            sred[wave][d]     = ls[d];
            sred[wave][D + d] = lq[d];
        }
    }
    __syncthreads();
    if (tid < D) {
        int d = tid;
        double S = sred[0][d] + sred[1][d] + sred[2][d] + sred[3][d];
        double Q = sred[0][D+d] + sred[1][D+d] + sred[2][D+d] + sred[3][D+d];
        double mean = S / (double)N;
        double var  = (Q - S * S / (double)N) / (double)(N - 1);
        if (var < 0.0) var = 0.0;
        float stdv = (float)sqrt(var);
        float scl  = 1.0f / (stdv + 1e-5f);
        float scl0 = 1.0f / (0.0f + 1e-5f);
        bool mask = features[b * D + d] > 0.1f;
        smean [d]      = mask ? 0.0f : (float)mean;
        sscale[d]      = mask ? scl0 : scl;
        smean [16 + d] = mask ? (float)mean : 0.0f;
        sscale[16 + d] = mask ? scl : scl0;
    }
    __syncthreads();

    // ---- per-point processing (identical arithmetic to rounds 1-5) ----
    int t = blockIdx.x * 256 + tid;
    float tc = 0.f, tf = 0.f, s = 0.f;
    float row[D];
#pragma unroll
    for (int d = 0; d < D; ++d) {
        float xv = x[(size_t)t * D + d];
        bool mask = features[b * D + d] > 0.1f;
        float xc = mask ? 0.f : xv;
        float xf = mask ? xv : 0.f;
        row[d] = xc;
        s += xc * xc;                            // sequential, mirrors ref sq
        float vc = (xc - smean[d])      * sscale[d];
        vc = fminf(10.f, fmaxf(-10.f, vc));
        float vf = (xf - smean[16 + d]) * sscale[16 + d];
        vf = fminf(10.f, fmaxf(-10.f, vf));
        tc += vc; tf += vf;
    }
#pragma unroll
    for (int d = 0; d < D; d += 4)
        *(float4*)(xcrd + (size_t)t * D + d) =
            make_float4(row[d], row[d+1], row[d+2], row[d+3]);
    sq[t] = s; Tc[t] = tc; Tf[t] = tf;
}

// ---------------------------------------------------------------------------
// K2: one wave per query.  Fill = round-5 bit-path (full 16-channel rows from
// xcrd).  Selection = f32 VALUE-only butterfly (1-inst fminf/fmaxf CEs,
// single-reg shuffles) for tau = exact 32nd-smallest distance, then exact
// tie-fixup: ballot-compact all dist<=tau in ascending-index order to LDS,
// rank by unique packed key (dist_bits<<11|m) == lexicographic (dist,idx).
// fabsf normalizes -0 so f32 bit order == numeric order in the packed key.
// ---------------------------------------------------------------------------
__global__ __launch_bounds__(64, 2) void knn_main(
    const float* __restrict__ xcrd, const float* __restrict__ sq,
    const float* __restrict__ Tc, const float* __restrict__ Tf,
    const float* __restrict__ WcT, const float* __restrict__ WfT,
    const float* __restrict__ cbias, float* __restrict__ out)
{
    __shared__ unsigned long long collect[CAP];
    __shared__ int sortedm[KNN];

    const int lane = threadIdx.x;
    const int qid  = blockIdx.x;                 // 0..16383
    const int b = qid >> 11;
    const int n = qid & (N - 1);

    const float* xb  = xcrd + (size_t)b * N * D;
    const float* sqb = sq + b * N;

    // query row
    float qx[D];
#pragma unroll
    for (int d = 0; d < D; d += 4) {
        float4 v = *(const float4*)(xb + (size_t)n * D + d);
        qx[d] = v.x; qx[d+1] = v.y; qx[d+2] = v.z; qx[d+3] = v.w;
    }
    const float sqn = sqb[n];

    // ---- fill: round-5 distance arithmetic, byte-identical ----
    float orig[KNN], srt[KNN];
#pragma unroll
    for (int j = 0; j < KNN; ++j) {
        int m = j * 64 + lane;
        const float* xm = xb + (size_t)m * D;
        float4 v0 = *(const float4*)(xm);
        float4 v1 = *(const float4*)(xm + 4);
        float4 v2 = *(const float4*)(xm + 8);
        float4 v3 = *(const float4*)(xm + 12);
        float dot = 0.f;
        dot += qx[0]  * v0.x; dot += qx[1]  * v0.y;
        dot += qx[2]  * v0.z; dot += qx[3]  * v0.w;
        dot += qx[4]  * v1.x; dot += qx[5]  * v1.y;
        dot += qx[6]  * v1.z; dot += qx[7]  * v1.w;
        dot += qx[8]  * v2.x; dot += qx[9]  * v2.y;
        dot += qx[10] * v2.z; dot += qx[11] * v2.w;
        dot += qx[12] * v3.x; dot += qx[13] * v3.y;
        dot += qx[14] * v3.z; dot += qx[15] * v3.w;
        float d2 = sqn + sqb[m] - 2.0f * dot;
        float dist = fabsf(sqrtf(fmaxf(d2, 0.f)));   // fabs: -0 -> +0
        orig[j] = dist; srt[j] = dist;
    }

    // ---- per-lane bitonic sort (ascending) of the value copy ----
#pragma unroll
    for (int kk = 2; kk <= KNN; kk <<= 1) {
#pragma unroll
        for (int jj = kk >> 1; jj > 0; jj >>= 1) {
#pragma unroll
            for (int i = 0; i < KNN; ++i) {
                int l = i ^ jj;
                if (l > i) {
                    float a = srt[i], c2 = srt[l];
                    if ((i & kk) == 0) { srt[i] = fminf(a, c2); srt[l] = fmaxf(a, c2); }
                    else               { srt[i] = fmaxf(a, c2); srt[l] = fminf(a, c2); }
                }
            }
        }
    }

    // ---- 6 butterfly min-32 merge rounds (values only, duplicates ok) ----
#pragma unroll 1
    for (int s = 1; s <= 32; s <<= 1) {
#pragma unroll
        for (int i = 0; i < KNN / 2; ++i) {
            int r = KNN - 1 - i;
            float o_i = __shfl_xor(srt[r], s, 64);   // partner[31-i]
            float o_r = __shfl_xor(srt[i], s, 64);   // partner[31-r]
            srt[i] = fminf(srt[i], o_i);
            srt[r] = fminf(srt[r], o_r);
        }
#pragma unroll
        for (int jj = 16; jj >= 1; jj >>= 1) {
#pragma unroll
            for (int i = 0; i < KNN; ++i) {
                if ((i & jj) == 0) {
                    int l = i + jj;
                    float a = srt[i], c2 = srt[l];
                    srt[i] = fminf(a, c2);
                    srt[l] = fmaxf(a, c2);
                }
            }
        }
    }
    const float tau = srt[31];                   // exact 32nd smallest value

    // ---- tie-fixup: compact all dist <= tau in ascending global-index order ----
    const unsigned long long lmask = (1ULL << lane) - 1ULL;
    int base = 0;
#pragma unroll
    for (int j = 0; j < KNN; ++j) {
        bool f = (orig[j] <= tau);
        unsigned long long mk = __ballot(f);
        if (f) {
            int pos = base + (int)__popcll(mk & lmask);
            if (pos < CAP)
                collect[pos] =
                    (((unsigned long long)__float_as_uint(orig[j])) << 11)
                    | (unsigned)(j * 64 + lane);
        }
        base += (int)__popcll(mk);
    }
    int T = base < CAP ? base : CAP;             // wave-uniform, >= 32
    __syncthreads();

    // ---- rank the T collected items (keys globally unique) ----
#pragma unroll 1
    for (int slot = 0; slot < 2; ++slot) {
        int i = lane + slot * 64;
        if (i < T) {
            unsigned long long mk = collect[i];
            int rank = 0;
#pragma unroll 1
            for (int t2 = 0; t2 < T; ++t2)
                rank += (collect[t2] < mk) ? 1 : 0;
            if (rank < KNN)
                sortedm[rank] = (int)(mk & 2047u);
        }
    }
    __syncthreads();

    // ---- matvec: ranked top-32 ----
    float acc[4] = {0.f, 0.f, 0.f, 0.f};
    const float* Tcb = Tc + b * N;
    const float* Tfb = Tf + b * N;
    const float Tcn = Tcb[n], Tfn = Tfb[n];

#pragma unroll
    for (int k = 0; k < KNN; ++k) {
        int wm = sortedm[k];
        float ak = Tcb[wm] - Tcn;
        float bk = Tfb[wm] - Tfn;
        const float* wc = WcT + k * DM + lane;
        const float* wf = WfT + k * DM + lane;
#pragma unroll
        for (int q = 0; q < 4; ++q)
            acc[q] += wc[q * 64] * ak + wf[q * 64] * bk;
    }

    size_t obase = (size_t)qid * DM + lane;
#pragma unroll
    for (int q = 0; q < 4; ++q)
        out[obase + q * 64] = acc[q] + cbias[lane + q * 64];
}

// ---------------------------------------------------------------------------
extern "C" void kernel_launch(void* const* d_in, const int* in_sizes, int n_in,
                              void* d_out, int out_size, void* d_ws, size_t ws_size,
                              hipStream_t stream)
{
    const float* x        = (const float*)d_in[0];   // (B,N,D)
    const float* features = (const float*)d_in[1];   // (B,D)
    const float* W_crd    = (const float*)d_in[2];   // (DM,K)
    const float* W_ftr    = (const float*)d_in[3];   // (DM,K)
    const float* pe_crd   = (const float*)d_in[4];   // (1,1,D,DM)
    const float* pe_ftr   = (const float*)d_in[5];   // (1,1,D,DM)
    // d_in[6] = k (constant 32), ignored

    float* out = (float*)d_out;                      // B*N*DM floats + 1 (pe_loss)

    float* xcrd  = (float*)d_ws;                     // 262144
    float* sqv   = xcrd + (size_t)B * N * D;         // 16384
    float* Tc    = sqv  + B * N;                     // 16384
    float* Tf    = Tc   + B * N;                     // 16384
    float* cbias = Tf   + B * N;                     // 256
    float* WcT   = cbias + DM;                       // 8192
    float* WfT   = WcT + KNN * DM;                   // 8192

    knn_prep<<<65, 256, 0, stream>>>(x, features, W_crd, W_ftr, pe_crd, pe_ftr,
                                     xcrd, sqv, Tc, Tf, WcT, WfT, cbias,
                                     out + (size_t)out_size - 1);
    knn_main<<<B * N, 64, 0, stream>>>(xcrd, sqv, Tc, Tf,
                                       WcT, WfT, cbias, out);
}